// Round 1
// baseline (3164.616 us; speedup 1.0000x reference)
//
#include <hip/hip_runtime.h>

constexpr int F_IN   = 256;
constexpr int HID    = 128;
constexpr int NGRAPH = 512;

// ---------------- degree / norm ----------------
__global__ void deg_kernel(const int* __restrict__ col, const float* __restrict__ w,
                           float* __restrict__ deg, int E) {
  int e = blockIdx.x * blockDim.x + threadIdx.x;
  if (e < E) atomicAdd(&deg[col[e]], w[e]);
}

__global__ void dinv_kernel(float* deg, int n) {
  int i = blockIdx.x * blockDim.x + threadIdx.x;
  if (i < n) { float d = deg[i]; deg[i] = d > 0.f ? rsqrtf(d) : 0.f; }
}

__global__ void norm_kernel(const int* __restrict__ row, const int* __restrict__ col,
                            const float* __restrict__ w, const float* __restrict__ dinv,
                            float* __restrict__ nrm, int E) {
  int e = blockIdx.x * blockDim.x + threadIdx.x;
  if (e < E) nrm[e] = dinv[row[e]] * w[e] * dinv[col[e]];
}

// ---------------- fp32 tiled GEMM: C = A @ [Binit | Broot] ----------------
// A: M x K row-major. Binit/Broot: K x 128 row-major. Cinit/Croot: M x 128.
// Tile 64x64, 256 threads, 4x4 per thread.
template<int K>
__global__ __launch_bounds__(256)
void gemm_split(const float* __restrict__ A,
                const float* __restrict__ Binit, const float* __restrict__ Broot,
                float* __restrict__ Cinit, float* __restrict__ Croot, int M) {
  __shared__ float As[16][65];   // [k][m], +1 pad breaks 16-way bank conflicts
  __shared__ float Bs[16][64];   // [k][n]
  const int tid = threadIdx.x;
  const int tx = tid & 15, ty = tid >> 4;
  const int bm = blockIdx.x * 64;
  const int half = blockIdx.y >> 1;          // 0 -> init, 1 -> root
  const int cb = (blockIdx.y & 1) * 64;      // column base within the 128-wide half
  const float* __restrict__ B = half ? Broot : Binit;
  float* __restrict__ C = half ? Croot : Cinit;

  float acc[4][4] = {};
  const int ar = tid >> 2;            // 0..63  (A row within tile)
  const int ak = (tid & 3) << 2;      // 0,4,8,12 (A k quad)
  const int bk = tid >> 4;            // 0..15 (B k)
  const int bn = (tid & 15) << 2;     // 0..60 (B n quad)

  for (int k0 = 0; k0 < K; k0 += 16) {
    float4 av = make_float4(0.f, 0.f, 0.f, 0.f);
    const int gr = bm + ar;
    if (gr < M) av = *reinterpret_cast<const float4*>(&A[(size_t)gr * K + k0 + ak]);
    As[ak + 0][ar] = av.x; As[ak + 1][ar] = av.y;
    As[ak + 2][ar] = av.z; As[ak + 3][ar] = av.w;
    const float4 bv = *reinterpret_cast<const float4*>(&B[(size_t)(k0 + bk) * HID + cb + bn]);
    *reinterpret_cast<float4*>(&Bs[bk][bn]) = bv;
    __syncthreads();
#pragma unroll
    for (int kk = 0; kk < 16; ++kk) {
      const float a0 = As[kk][ty * 4 + 0], a1 = As[kk][ty * 4 + 1];
      const float a2 = As[kk][ty * 4 + 2], a3 = As[kk][ty * 4 + 3];
      const float b0 = Bs[kk][tx * 4 + 0], b1 = Bs[kk][tx * 4 + 1];
      const float b2 = Bs[kk][tx * 4 + 2], b3 = Bs[kk][tx * 4 + 3];
      acc[0][0] = fmaf(a0, b0, acc[0][0]); acc[0][1] = fmaf(a0, b1, acc[0][1]);
      acc[0][2] = fmaf(a0, b2, acc[0][2]); acc[0][3] = fmaf(a0, b3, acc[0][3]);
      acc[1][0] = fmaf(a1, b0, acc[1][0]); acc[1][1] = fmaf(a1, b1, acc[1][1]);
      acc[1][2] = fmaf(a1, b2, acc[1][2]); acc[1][3] = fmaf(a1, b3, acc[1][3]);
      acc[2][0] = fmaf(a2, b0, acc[2][0]); acc[2][1] = fmaf(a2, b1, acc[2][1]);
      acc[2][2] = fmaf(a2, b2, acc[2][2]); acc[2][3] = fmaf(a2, b3, acc[2][3]);
      acc[3][0] = fmaf(a3, b0, acc[3][0]); acc[3][1] = fmaf(a3, b1, acc[3][1]);
      acc[3][2] = fmaf(a3, b2, acc[3][2]); acc[3][3] = fmaf(a3, b3, acc[3][3]);
    }
    __syncthreads();
  }
#pragma unroll
  for (int i = 0; i < 4; ++i) {
    const int gr = bm + ty * 4 + i;
    if (gr < M) {
      float4 v = make_float4(acc[i][0], acc[i][1], acc[i][2], acc[i][3]);
      *reinterpret_cast<float4*>(&C[(size_t)gr * HID + cb + tx * 4]) = v;
    }
  }
}

// ---------------- edge gather+scatter: agg[col] += norm * H[row] ----------------
__global__ __launch_bounds__(256)
void scatter_kernel(const int* __restrict__ row, const int* __restrict__ col,
                    const float* __restrict__ nrm, const float* __restrict__ H,
                    float* __restrict__ agg, int E) {
  const int lane = threadIdx.x & 63;
  int wid = blockIdx.x * 4 + (threadIdx.x >> 6);
  const int nw = gridDim.x * 4;
  for (int e = wid; e < E; e += nw) {
    const int r = row[e], c = col[e];
    const float nv = nrm[e];
    const float2 hv = *reinterpret_cast<const float2*>(&H[(size_t)r * HID + lane * 2]);
    atomicAdd(&agg[(size_t)c * HID + lane * 2 + 0], nv * hv.x);
    atomicAdd(&agg[(size_t)c * HID + lane * 2 + 1], nv * hv.y);
  }
}

// ---------------- h = relu(agg + root + b), written in place over root ----------------
__global__ void combine_relu_kernel(const float* __restrict__ agg, float* __restrict__ root_io,
                                    const float* __restrict__ bias, int total4) {
  int i = blockIdx.x * blockDim.x + threadIdx.x;
  if (i >= total4) return;
  const int f4 = i & (HID / 4 - 1);
  const float4 a = reinterpret_cast<const float4*>(agg)[i];
  const float4 r = reinterpret_cast<const float4*>(root_io)[i];
  const float4 b = reinterpret_cast<const float4*>(bias)[f4];
  float4 o;
  o.x = fmaxf(a.x + r.x + b.x, 0.f);
  o.y = fmaxf(a.y + r.y + b.y, 0.f);
  o.z = fmaxf(a.z + r.z + b.z, 0.f);
  o.w = fmaxf(a.w + r.w + b.w, 0.f);
  reinterpret_cast<float4*>(root_io)[i] = o;
}

// ---------------- conv1 epilogue fused with mean-pool accumulation ----------------
// batch is sorted: accumulate runs of equal graph id in registers, flush on change.
__global__ __launch_bounds__(128)
void combine_pool_kernel(const float* __restrict__ agg, const float* __restrict__ root,
                         const float* __restrict__ bias, const int* __restrict__ batch,
                         float* __restrict__ gsum, int N) {
  const int f = threadIdx.x;
  const float bf = bias[f];
  const int i0 = blockIdx.x * 16;
  const int i1 = min(i0 + 16, N);
  float acc = 0.f; int curg = -1;
  for (int i = i0; i < i1; ++i) {
    const int g = batch[i];
    const float v = fmaxf(agg[(size_t)i * HID + f] + root[(size_t)i * HID + f] + bf, 0.f);
    if (g != curg) {
      if (curg >= 0) atomicAdd(&gsum[curg * HID + f], acc);
      acc = 0.f; curg = g;
    }
    acc += v;
  }
  if (curg >= 0) atomicAdd(&gsum[curg * HID + f], acc);
}

__global__ void count_kernel(const int* __restrict__ batch, float* __restrict__ gcnt, int N) {
  int i = blockIdx.x * blockDim.x + threadIdx.x;
  if (i < N) atomicAdd(&gcnt[batch[i]], 1.f);
}

// ---------------- graph MLP: out = relu(gx@w1+b1)@w2 + b2 ----------------
__global__ __launch_bounds__(256)
void mlp_kernel(const float* __restrict__ gsum, const float* __restrict__ gcnt,
                const float* __restrict__ w1, const float* __restrict__ b1,
                const float* __restrict__ w2, const float* __restrict__ b2,
                float* __restrict__ out) {
  const int g = blockIdx.x;
  const int t = threadIdx.x;
  __shared__ float gx[HID];
  __shared__ float red[8];
  const float cnt = fmaxf(gcnt[g], 1.f);
  if (t < HID) gx[t] = gsum[g * HID + t] / cnt;
  __syncthreads();
  float a = b1[t];
  for (int k = 0; k < HID; ++k) a = fmaf(gx[k], w1[k * 256 + t], a);
  const float h = fmaxf(a, 0.f);
  float p0 = h * w2[t * 2 + 0];
  float p1 = h * w2[t * 2 + 1];
  for (int o = 32; o > 0; o >>= 1) { p0 += __shfl_down(p0, o, 64); p1 += __shfl_down(p1, o, 64); }
  const int lane = t & 63, wv = t >> 6;
  if (lane == 0) { red[wv * 2] = p0; red[wv * 2 + 1] = p1; }
  __syncthreads();
  if (t == 0) out[g * 2 + 0] = red[0] + red[2] + red[4] + red[6] + b2[0];
  if (t == 1) out[g * 2 + 1] = red[1] + red[3] + red[5] + red[7] + b2[1];
}

extern "C" void kernel_launch(void* const* d_in, const int* in_sizes, int n_in,
                              void* d_out, int out_size, void* d_ws, size_t ws_size,
                              hipStream_t stream) {
  const float* x       = (const float*)d_in[0];
  const int*   ei      = (const int*)d_in[1];
  const float* ea      = (const float*)d_in[2];
  const int*   batch   = (const int*)d_in[3];
  const float* w_init0 = (const float*)d_in[4];
  const float* w_root0 = (const float*)d_in[5];
  const float* b0      = (const float*)d_in[6];
  const float* w_init1 = (const float*)d_in[7];
  const float* w_root1 = (const float*)d_in[8];
  const float* b1      = (const float*)d_in[9];
  const float* mw1     = (const float*)d_in[10];
  const float* mb1     = (const float*)d_in[11];
  const float* mw2     = (const float*)d_in[12];
  const float* mb2     = (const float*)d_in[13];
  float* out = (float*)d_out;

  const int E = in_sizes[2];     // edge_attr element count
  const int N = in_sizes[3];     // batch element count
  const int* row = ei;
  const int* col = ei + E;

  char* ws = (char*)d_ws;
  size_t off = 0;
  auto alloc = [&](size_t bytes) -> void* {
    size_t cur = off;
    off = (cur + bytes + 255) & ~(size_t)255;
    return (void*)(ws + cur);
  };
  float* deg  = (float*)alloc((size_t)N * 4);
  float* nrm  = (float*)alloc((size_t)E * 4);
  float* B1   = (float*)alloc((size_t)N * HID * 4);   // x@w_init / h@w_init
  float* B2   = (float*)alloc((size_t)N * HID * 4);   // x@w_root -> h -> agg1
  float* B3   = (float*)alloc((size_t)N * HID * 4);   // agg0 -> h@w_root
  float* gsum = (float*)alloc((size_t)NGRAPH * HID * 4);
  float* gcnt = (float*)alloc((size_t)NGRAPH * 4);
  (void)ws_size; (void)n_in; (void)out_size;

  // ---- gcn_norm ----
  hipMemsetAsync(deg, 0, (size_t)N * 4, stream);
  deg_kernel<<<(E + 255) / 256, 256, 0, stream>>>(col, ea, deg, E);
  dinv_kernel<<<(N + 255) / 256, 256, 0, stream>>>(deg, N);
  norm_kernel<<<(E + 255) / 256, 256, 0, stream>>>(row, col, ea, deg, nrm, E);

  const dim3 gg((N + 63) / 64, 4);

  // ---- conv0 ----
  gemm_split<F_IN><<<gg, 256, 0, stream>>>(x, w_init0, w_root0, B1, B2, N);
  hipMemsetAsync(B3, 0, (size_t)N * HID * 4, stream);
  scatter_kernel<<<4096, 256, 0, stream>>>(row, col, nrm, B1, B3, E);
  combine_relu_kernel<<<(N * HID / 4 + 255) / 256, 256, 0, stream>>>(B3, B2, b0, N * HID / 4);

  // ---- conv1 ----
  gemm_split<HID><<<gg, 256, 0, stream>>>(B2, w_init1, w_root1, B1, B3, N);
  hipMemsetAsync(B2, 0, (size_t)N * HID * 4, stream);
  scatter_kernel<<<4096, 256, 0, stream>>>(row, col, nrm, B1, B2, E);

  // ---- pool + MLP ----
  hipMemsetAsync(gsum, 0, (size_t)NGRAPH * HID * 4, stream);
  hipMemsetAsync(gcnt, 0, (size_t)NGRAPH * 4, stream);
  combine_pool_kernel<<<(N + 15) / 16, 128, 0, stream>>>(B2, B3, b1, batch, gsum, N);
  count_kernel<<<(N + 255) / 256, 256, 0, stream>>>(batch, gcnt, N);
  mlp_kernel<<<NGRAPH, 256, 0, stream>>>(gsum, gcnt, mw1, mb1, mw2, mb2, out);
}

// Round 2
// 978.574 us; speedup vs baseline: 3.2339x; 3.2339x over previous
//
#include <hip/hip_runtime.h>

constexpr int F_IN   = 256;
constexpr int HID    = 128;
constexpr int NGRAPH = 512;

// ---------------- degree ----------------
__global__ void deg_kernel(const int* __restrict__ col, const float* __restrict__ w,
                           float* __restrict__ deg, int E) {
  int e = blockIdx.x * blockDim.x + threadIdx.x;
  if (e < E) atomicAdd(&deg[col[e]], w[e]);
}

__global__ void dinv_kernel(float* deg, int n) {
  int i = blockIdx.x * blockDim.x + threadIdx.x;
  if (i < n) { float d = deg[i]; deg[i] = d > 0.f ? rsqrtf(d) : 0.f; }
}

// ---------------- CSR build (by destination col) ----------------
__global__ void count_in_kernel(const int* __restrict__ col, int* __restrict__ cnt, int E) {
  int e = blockIdx.x * blockDim.x + threadIdx.x;
  if (e < E) atomicAdd(&cnt[col[e]], 1);
}

__global__ void scan1_kernel(const int* __restrict__ cnt, int* __restrict__ psum, int N) {
  __shared__ int s[256];
  int i = blockIdx.x * 256 + threadIdx.x;
  s[threadIdx.x] = (i < N) ? cnt[i] : 0;
  __syncthreads();
  for (int o = 128; o > 0; o >>= 1) {
    if (threadIdx.x < o) s[threadIdx.x] += s[threadIdx.x + o];
    __syncthreads();
  }
  if (threadIdx.x == 0) psum[blockIdx.x] = s[0];
}

__global__ void scan2_kernel(int* __restrict__ psum, int nb) {
  if (threadIdx.x == 0 && blockIdx.x == 0) {
    int acc = 0;
    for (int i = 0; i < nb; ++i) { int v = psum[i]; psum[i] = acc; acc += v; }
  }
}

__global__ void scan3_kernel(const int* __restrict__ cnt, const int* __restrict__ psum,
                             int* __restrict__ rowptr, int N, int E) {
  __shared__ int s[256];
  int i = blockIdx.x * 256 + threadIdx.x;
  int v = (i < N) ? cnt[i] : 0;
  s[threadIdx.x] = v;
  __syncthreads();
  for (int o = 1; o < 256; o <<= 1) {
    int t = (threadIdx.x >= o) ? s[threadIdx.x - o] : 0;
    __syncthreads();
    s[threadIdx.x] += t;
    __syncthreads();
  }
  if (i < N) rowptr[i] = psum[blockIdx.x] + s[threadIdx.x] - v;   // exclusive
  if (i == 0) rowptr[N] = E;
}

// fill CSR payload; norm computed inline: dinv[row]*w*dinv[col]
__global__ void fill_csr_kernel(const int* __restrict__ row, const int* __restrict__ col,
                                const float* __restrict__ ew, const float* __restrict__ dinv,
                                const int* __restrict__ rowptr, int* __restrict__ cursor,
                                int* __restrict__ crow, float* __restrict__ cnrm, int E) {
  int e = blockIdx.x * blockDim.x + threadIdx.x;
  if (e >= E) return;
  const int r = row[e], c = col[e];
  const int p = rowptr[c] + atomicAdd(&cursor[c], 1);
  crow[p] = r;
  cnrm[p] = dinv[r] * ew[e] * dinv[c];
}

// ---------------- fp32 tiled GEMM: C = A @ [Binit | Broot] ----------------
template<int K>
__global__ __launch_bounds__(256)
void gemm_split(const float* __restrict__ A,
                const float* __restrict__ Binit, const float* __restrict__ Broot,
                float* __restrict__ Cinit, float* __restrict__ Croot, int M) {
  __shared__ float As[16][65];
  __shared__ float Bs[16][64];
  const int tid = threadIdx.x;
  const int tx = tid & 15, ty = tid >> 4;
  const int bm = blockIdx.x * 64;
  const int half = blockIdx.y >> 1;
  const int cb = (blockIdx.y & 1) * 64;
  const float* __restrict__ B = half ? Broot : Binit;
  float* __restrict__ C = half ? Croot : Cinit;

  float acc[4][4] = {};
  const int ar = tid >> 2;
  const int ak = (tid & 3) << 2;
  const int bk = tid >> 4;
  const int bn = (tid & 15) << 2;

  for (int k0 = 0; k0 < K; k0 += 16) {
    float4 av = make_float4(0.f, 0.f, 0.f, 0.f);
    const int gr = bm + ar;
    if (gr < M) av = *reinterpret_cast<const float4*>(&A[(size_t)gr * K + k0 + ak]);
    As[ak + 0][ar] = av.x; As[ak + 1][ar] = av.y;
    As[ak + 2][ar] = av.z; As[ak + 3][ar] = av.w;
    const float4 bv = *reinterpret_cast<const float4*>(&B[(size_t)(k0 + bk) * HID + cb + bn]);
    *reinterpret_cast<float4*>(&Bs[bk][bn]) = bv;
    __syncthreads();
#pragma unroll
    for (int kk = 0; kk < 16; ++kk) {
      const float a0 = As[kk][ty * 4 + 0], a1 = As[kk][ty * 4 + 1];
      const float a2 = As[kk][ty * 4 + 2], a3 = As[kk][ty * 4 + 3];
      const float b0 = Bs[kk][tx * 4 + 0], b1 = Bs[kk][tx * 4 + 1];
      const float b2 = Bs[kk][tx * 4 + 2], b3 = Bs[kk][tx * 4 + 3];
      acc[0][0] = fmaf(a0, b0, acc[0][0]); acc[0][1] = fmaf(a0, b1, acc[0][1]);
      acc[0][2] = fmaf(a0, b2, acc[0][2]); acc[0][3] = fmaf(a0, b3, acc[0][3]);
      acc[1][0] = fmaf(a1, b0, acc[1][0]); acc[1][1] = fmaf(a1, b1, acc[1][1]);
      acc[1][2] = fmaf(a1, b2, acc[1][2]); acc[1][3] = fmaf(a1, b3, acc[1][3]);
      acc[2][0] = fmaf(a2, b0, acc[2][0]); acc[2][1] = fmaf(a2, b1, acc[2][1]);
      acc[2][2] = fmaf(a2, b2, acc[2][2]); acc[2][3] = fmaf(a2, b3, acc[2][3]);
      acc[3][0] = fmaf(a3, b0, acc[3][0]); acc[3][1] = fmaf(a3, b1, acc[3][1]);
      acc[3][2] = fmaf(a3, b2, acc[3][2]); acc[3][3] = fmaf(a3, b3, acc[3][3]);
    }
    __syncthreads();
  }
#pragma unroll
  for (int i = 0; i < 4; ++i) {
    const int gr = bm + ty * 4 + i;
    if (gr < M) {
      float4 v = make_float4(acc[i][0], acc[i][1], acc[i][2], acc[i][3]);
      *reinterpret_cast<float4*>(&C[(size_t)gr * HID + cb + tx * 4]) = v;
    }
  }
}

// ---------------- pull-gather conv: out[n] = relu(sum_e nrm*H[row] + root[n] + b) ----------------
// one wave (64 lanes) per node; 2 features per lane.
__global__ __launch_bounds__(256)
void gather_kernel(const int* __restrict__ rowptr, const int* __restrict__ crow,
                   const float* __restrict__ cnrm, const float* __restrict__ H,
                   const float* __restrict__ root, const float* __restrict__ bias,
                   float* __restrict__ out, int N) {
  const int lane = threadIdx.x & 63;
  const int node = blockIdx.x * 4 + (threadIdx.x >> 6);
  if (node >= N) return;
  const int s = rowptr[node], t = rowptr[node + 1];
  float a0 = 0.f, a1 = 0.f;
  for (int p0 = s; p0 < t; p0 += 64) {
    const int np = min(64, t - p0);
    const int  r = (p0 + lane < t) ? crow[p0 + lane] : 0;
    const float w = (p0 + lane < t) ? cnrm[p0 + lane] : 0.f;
    for (int j = 0; j < np; ++j) {
      const int   rj = __shfl(r, j, 64);
      const float wj = __shfl(w, j, 64);
      const float2 hv = *reinterpret_cast<const float2*>(&H[(size_t)rj * HID + lane * 2]);
      a0 = fmaf(wj, hv.x, a0);
      a1 = fmaf(wj, hv.y, a1);
    }
  }
  const float2 rv = *reinterpret_cast<const float2*>(&root[(size_t)node * HID + lane * 2]);
  float2 o;
  o.x = fmaxf(a0 + rv.x + bias[lane * 2 + 0], 0.f);
  o.y = fmaxf(a1 + rv.y + bias[lane * 2 + 1], 0.f);
  *reinterpret_cast<float2*>(&out[(size_t)node * HID + lane * 2]) = o;
}

// ---------------- mean-pool accumulation (batch sorted: register runs) ----------------
__global__ __launch_bounds__(128)
void pool_kernel(const float* __restrict__ node_x, const int* __restrict__ batch,
                 float* __restrict__ gsum, int N) {
  const int f = threadIdx.x;
  const int i0 = blockIdx.x * 16;
  const int i1 = min(i0 + 16, N);
  float acc = 0.f; int curg = -1;
  for (int i = i0; i < i1; ++i) {
    const int g = batch[i];
    const float v = node_x[(size_t)i * HID + f];
    if (g != curg) {
      if (curg >= 0) atomicAdd(&gsum[curg * HID + f], acc);
      acc = 0.f; curg = g;
    }
    acc += v;
  }
  if (curg >= 0) atomicAdd(&gsum[curg * HID + f], acc);
}

__global__ void count_kernel(const int* __restrict__ batch, float* __restrict__ gcnt, int N) {
  int i = blockIdx.x * blockDim.x + threadIdx.x;
  if (i < N) atomicAdd(&gcnt[batch[i]], 1.f);
}

// ---------------- graph MLP ----------------
__global__ __launch_bounds__(256)
void mlp_kernel(const float* __restrict__ gsum, const float* __restrict__ gcnt,
                const float* __restrict__ w1, const float* __restrict__ b1,
                const float* __restrict__ w2, const float* __restrict__ b2,
                float* __restrict__ out) {
  const int g = blockIdx.x;
  const int t = threadIdx.x;
  __shared__ float gx[HID];
  __shared__ float red[8];
  const float cnt = fmaxf(gcnt[g], 1.f);
  if (t < HID) gx[t] = gsum[g * HID + t] / cnt;
  __syncthreads();
  float a = b1[t];
  for (int k = 0; k < HID; ++k) a = fmaf(gx[k], w1[k * 256 + t], a);
  const float h = fmaxf(a, 0.f);
  float p0 = h * w2[t * 2 + 0];
  float p1 = h * w2[t * 2 + 1];
  for (int o = 32; o > 0; o >>= 1) { p0 += __shfl_down(p0, o, 64); p1 += __shfl_down(p1, o, 64); }
  const int lane = t & 63, wv = t >> 6;
  if (lane == 0) { red[wv * 2] = p0; red[wv * 2 + 1] = p1; }
  __syncthreads();
  if (t == 0) out[g * 2 + 0] = red[0] + red[2] + red[4] + red[6] + b2[0];
  if (t == 1) out[g * 2 + 1] = red[1] + red[3] + red[5] + red[7] + b2[1];
}

extern "C" void kernel_launch(void* const* d_in, const int* in_sizes, int n_in,
                              void* d_out, int out_size, void* d_ws, size_t ws_size,
                              hipStream_t stream) {
  const float* x       = (const float*)d_in[0];
  const int*   ei      = (const int*)d_in[1];
  const float* ea      = (const float*)d_in[2];
  const int*   batch   = (const int*)d_in[3];
  const float* w_init0 = (const float*)d_in[4];
  const float* w_root0 = (const float*)d_in[5];
  const float* b0      = (const float*)d_in[6];
  const float* w_init1 = (const float*)d_in[7];
  const float* w_root1 = (const float*)d_in[8];
  const float* b1      = (const float*)d_in[9];
  const float* mw1     = (const float*)d_in[10];
  const float* mb1     = (const float*)d_in[11];
  const float* mw2     = (const float*)d_in[12];
  const float* mb2     = (const float*)d_in[13];
  float* out = (float*)d_out;

  const int E = in_sizes[2];
  const int N = in_sizes[3];
  const int* row = ei;
  const int* col = ei + E;
  const int nb = (N + 255) / 256;

  char* ws = (char*)d_ws;
  size_t off = 0;
  auto alloc = [&](size_t bytes) -> void* {
    size_t cur = off;
    off = (cur + bytes + 255) & ~(size_t)255;
    return (void*)(ws + cur);
  };
  float* deg    = (float*)alloc((size_t)N * 4);          // -> dinv in place
  int*   cnt    = (int*)alloc((size_t)N * 4);
  int*   cursor = (int*)alloc((size_t)N * 4);
  int*   psum   = (int*)alloc((size_t)nb * 4);
  int*   rowptr = (int*)alloc((size_t)(N + 1) * 4);
  int*   crow   = (int*)alloc((size_t)E * 4);
  float* cnrm   = (float*)alloc((size_t)E * 4);
  float* B1     = (float*)alloc((size_t)N * HID * 4);    // h@w_init
  float* B2     = (float*)alloc((size_t)N * HID * 4);    // x@w_root -> h
  float* B3     = (float*)alloc((size_t)N * HID * 4);    // h@w_root -> node_x
  float* gsum   = (float*)alloc((size_t)NGRAPH * HID * 4);
  float* gcnt   = (float*)alloc((size_t)NGRAPH * 4);
  (void)ws_size; (void)n_in; (void)out_size;

  // ---- gcn_norm + CSR build ----
  hipMemsetAsync(deg, 0, (size_t)N * 4, stream);
  hipMemsetAsync(cnt, 0, (size_t)N * 4, stream);
  hipMemsetAsync(cursor, 0, (size_t)N * 4, stream);
  deg_kernel<<<(E + 255) / 256, 256, 0, stream>>>(col, ea, deg, E);
  dinv_kernel<<<(N + 255) / 256, 256, 0, stream>>>(deg, N);
  count_in_kernel<<<(E + 255) / 256, 256, 0, stream>>>(col, cnt, E);
  scan1_kernel<<<nb, 256, 0, stream>>>(cnt, psum, N);
  scan2_kernel<<<1, 64, 0, stream>>>(psum, nb);
  scan3_kernel<<<nb, 256, 0, stream>>>(cnt, psum, rowptr, N, E);
  fill_csr_kernel<<<(E + 255) / 256, 256, 0, stream>>>(row, col, ea, deg, rowptr, cursor,
                                                       crow, cnrm, E);

  const dim3 gg((N + 63) / 64, 4);

  // ---- conv0: B1 = x@w_init0, B2 = x@w_root0; B2 <- relu(gather(B1) + B2 + b0) ----
  gemm_split<F_IN><<<gg, 256, 0, stream>>>(x, w_init0, w_root0, B1, B2, N);
  gather_kernel<<<(N + 3) / 4, 256, 0, stream>>>(rowptr, crow, cnrm, B1, B2, b0, B2, N);

  // ---- conv1: B1 = h@w_init1, B3 = h@w_root1; B3 <- relu(gather(B1) + B3 + b1) ----
  gemm_split<HID><<<gg, 256, 0, stream>>>(B2, w_init1, w_root1, B1, B3, N);
  gather_kernel<<<(N + 3) / 4, 256, 0, stream>>>(rowptr, crow, cnrm, B1, B3, b1, B3, N);

  // ---- pool + MLP ----
  hipMemsetAsync(gsum, 0, (size_t)NGRAPH * HID * 4, stream);
  hipMemsetAsync(gcnt, 0, (size_t)NGRAPH * 4, stream);
  pool_kernel<<<(N + 15) / 16, 128, 0, stream>>>(B3, batch, gsum, N);
  count_kernel<<<(N + 255) / 256, 256, 0, stream>>>(batch, gcnt, N);
  mlp_kernel<<<NGRAPH, 256, 0, stream>>>(gsum, gcnt, mw1, mb1, mw2, mb2, out);
}

// Round 3
// 891.118 us; speedup vs baseline: 3.5513x; 1.0981x over previous
//
#include <hip/hip_runtime.h>

constexpr int F_IN   = 256;
constexpr int HID    = 128;
constexpr int NGRAPH = 512;

typedef short  short8 __attribute__((ext_vector_type(8)));
typedef float  f32x4  __attribute__((ext_vector_type(4)));

// round-to-nearest-even fp32 -> bf16 (as ushort), and back
__device__ __forceinline__ unsigned short f2bf(float f) {
  union { float f; unsigned int u; } v = { f };
  unsigned int r = v.u + 0x7fffu + ((v.u >> 16) & 1u);
  return (unsigned short)(r >> 16);
}
__device__ __forceinline__ float bf2f(unsigned short h) {
  union { unsigned int u; float f; } v;
  v.u = ((unsigned int)h) << 16;
  return v.f;
}

// ---------------- degree ----------------
__global__ void deg_kernel(const int* __restrict__ col, const float* __restrict__ w,
                           float* __restrict__ deg, int E) {
  int e = blockIdx.x * blockDim.x + threadIdx.x;
  if (e < E) atomicAdd(&deg[col[e]], w[e]);
}

__global__ void dinv_kernel(float* deg, int n) {
  int i = blockIdx.x * blockDim.x + threadIdx.x;
  if (i < n) { float d = deg[i]; deg[i] = d > 0.f ? rsqrtf(d) : 0.f; }
}

// ---------------- CSR build (by destination col) ----------------
__global__ void count_in_kernel(const int* __restrict__ col, int* __restrict__ cnt, int E) {
  int e = blockIdx.x * blockDim.x + threadIdx.x;
  if (e < E) atomicAdd(&cnt[col[e]], 1);
}

__global__ void scan1_kernel(const int* __restrict__ cnt, int* __restrict__ psum, int N) {
  __shared__ int s[256];
  int i = blockIdx.x * 256 + threadIdx.x;
  s[threadIdx.x] = (i < N) ? cnt[i] : 0;
  __syncthreads();
  for (int o = 128; o > 0; o >>= 1) {
    if (threadIdx.x < o) s[threadIdx.x] += s[threadIdx.x + o];
    __syncthreads();
  }
  if (threadIdx.x == 0) psum[blockIdx.x] = s[0];
}

__global__ void scan2_kernel(int* __restrict__ psum, int nb) {
  if (threadIdx.x == 0 && blockIdx.x == 0) {
    int acc = 0;
    for (int i = 0; i < nb; ++i) { int v = psum[i]; psum[i] = acc; acc += v; }
  }
}

__global__ void scan3_kernel(const int* __restrict__ cnt, const int* __restrict__ psum,
                             int* __restrict__ rowptr, int N, int E) {
  __shared__ int s[256];
  int i = blockIdx.x * 256 + threadIdx.x;
  int v = (i < N) ? cnt[i] : 0;
  s[threadIdx.x] = v;
  __syncthreads();
  for (int o = 1; o < 256; o <<= 1) {
    int t = (threadIdx.x >= o) ? s[threadIdx.x - o] : 0;
    __syncthreads();
    s[threadIdx.x] += t;
    __syncthreads();
  }
  if (i < N) rowptr[i] = psum[blockIdx.x] + s[threadIdx.x] - v;   // exclusive
  if (i == 0) rowptr[N] = E;
}

__global__ void fill_csr_kernel(const int* __restrict__ row, const int* __restrict__ col,
                                const float* __restrict__ ew, const float* __restrict__ dinv,
                                const int* __restrict__ rowptr, int* __restrict__ cursor,
                                int* __restrict__ crow, float* __restrict__ cnrm, int E) {
  int e = blockIdx.x * blockDim.x + threadIdx.x;
  if (e >= E) return;
  const int r = row[e], c = col[e];
  const int p = rowptr[c] + atomicAdd(&cursor[c], 1);
  crow[p] = r;
  cnrm[p] = dinv[r] * ew[e] * dinv[c];
}

// ---------------- weight prep: Bt[n][k] = [w_init | w_root], split hi/lo bf16 ----------------
// w_init, w_root: [K][128] fp32.  Bt_hi/Bt_lo: [256][K] bf16(ushort).
__global__ void prep_w_kernel(const float* __restrict__ wi, const float* __restrict__ wr,
                              unsigned short* __restrict__ bth, unsigned short* __restrict__ btl,
                              int K) {
  int idx = blockIdx.x * 256 + threadIdx.x;
  if (idx >= 256 * K) return;
  const int n = idx / K, k = idx - n * K;
  const float f = (n < HID) ? wi[k * HID + n] : wr[k * HID + (n - HID)];
  const unsigned short h = f2bf(f);
  bth[idx] = h;
  btl[idx] = f2bf(f - bf2f(h));
}

// ---------------- split-bf16 MFMA GEMM: [Cinit|Croot] = A @ Bt^T ----------------
// A: [M][K] fp32 row-major. Bt_hi/lo: [256][K] bf16. C*: [M][128] fp32.
// Block: 256 threads = 4 waves; block tile 64 rows x 256 cols; wave tile 64x64.
// C = Ah*Bh + Al*Bh + Ah*Bl  (error ~2^-17, fp32-equivalent here).
template<int K>
__global__ __launch_bounds__(256)
void gemm_mfma(const float* __restrict__ A,
               const unsigned short* __restrict__ Bth, const unsigned short* __restrict__ Btl,
               float* __restrict__ Cinit, float* __restrict__ Croot, int M) {
  const int lane = threadIdx.x & 63;
  const int wave = threadIdx.x >> 6;
  const int m0   = blockIdx.x * 64;
  const int cb   = wave * 64;          // this wave's column base (0..192)
  const int lr   = lane & 15;          // frag row (A) / frag col (B, C)
  const int lk   = (lane >> 4) * 8;    // frag k-chunk base

  f32x4 acc[4][4] = {};                // [mi][ni]

  for (int k0 = 0; k0 < K; k0 += 32) {
    short8 ah[4], al[4];
#pragma unroll
    for (int mi = 0; mi < 4; ++mi) {
      int row = m0 + mi * 16 + lr;
      row = row < M ? row : M - 1;     // clamp: only pollutes rows >= M (never stored)
      const float* p = &A[(size_t)row * K + k0 + lk];
      const float4 f0 = *reinterpret_cast<const float4*>(p);
      const float4 f1 = *reinterpret_cast<const float4*>(p + 4);
      const float f[8] = { f0.x, f0.y, f0.z, f0.w, f1.x, f1.y, f1.z, f1.w };
#pragma unroll
      for (int j = 0; j < 8; ++j) {
        const unsigned short h = f2bf(f[j]);
        ah[mi][j] = (short)h;
        al[mi][j] = (short)f2bf(f[j] - bf2f(h));
      }
    }
#pragma unroll
    for (int ni = 0; ni < 4; ++ni) {
      const int col = cb + ni * 16 + lr;
      const short8 bh = *reinterpret_cast<const short8*>(&Bth[(size_t)col * K + k0 + lk]);
      const short8 bl = *reinterpret_cast<const short8*>(&Btl[(size_t)col * K + k0 + lk]);
#pragma unroll
      for (int mi = 0; mi < 4; ++mi) {
        acc[mi][ni] = __builtin_amdgcn_mfma_f32_16x16x32_bf16(ah[mi], bh, acc[mi][ni], 0, 0, 0);
        acc[mi][ni] = __builtin_amdgcn_mfma_f32_16x16x32_bf16(al[mi], bh, acc[mi][ni], 0, 0, 0);
        acc[mi][ni] = __builtin_amdgcn_mfma_f32_16x16x32_bf16(ah[mi], bl, acc[mi][ni], 0, 0, 0);
      }
    }
  }

  // epilogue: C/D layout col = lane&15, row = (lane>>4)*4 + r
#pragma unroll
  for (int mi = 0; mi < 4; ++mi) {
#pragma unroll
    for (int ni = 0; ni < 4; ++ni) {
      const int col = cb + ni * 16 + lr;
      float* Cp = (col < HID) ? Cinit : Croot;
      const int ccol = (col < HID) ? col : col - HID;
#pragma unroll
      for (int r = 0; r < 4; ++r) {
        const int row = m0 + mi * 16 + (lane >> 4) * 4 + r;
        if (row < M) Cp[(size_t)row * HID + ccol] = acc[mi][ni][r];
      }
    }
  }
}

// ---------------- pull-gather conv: out[n] = relu(sum_e nrm*H[row] + root[n] + b) ----------------
__global__ __launch_bounds__(256)
void gather_kernel(const int* __restrict__ rowptr, const int* __restrict__ crow,
                   const float* __restrict__ cnrm, const float* __restrict__ H,
                   const float* __restrict__ root, const float* __restrict__ bias,
                   float* __restrict__ out, int N) {
  const int lane = threadIdx.x & 63;
  const int node = blockIdx.x * 4 + (threadIdx.x >> 6);
  if (node >= N) return;
  const int s = rowptr[node], t = rowptr[node + 1];
  float a0 = 0.f, a1 = 0.f;
  for (int p0 = s; p0 < t; p0 += 64) {
    const int np = min(64, t - p0);
    const int  r = (p0 + lane < t) ? crow[p0 + lane] : 0;
    const float w = (p0 + lane < t) ? cnrm[p0 + lane] : 0.f;
    for (int j = 0; j < np; ++j) {
      const int   rj = __shfl(r, j, 64);
      const float wj = __shfl(w, j, 64);
      const float2 hv = *reinterpret_cast<const float2*>(&H[(size_t)rj * HID + lane * 2]);
      a0 = fmaf(wj, hv.x, a0);
      a1 = fmaf(wj, hv.y, a1);
    }
  }
  const float2 rv = *reinterpret_cast<const float2*>(&root[(size_t)node * HID + lane * 2]);
  float2 o;
  o.x = fmaxf(a0 + rv.x + bias[lane * 2 + 0], 0.f);
  o.y = fmaxf(a1 + rv.y + bias[lane * 2 + 1], 0.f);
  *reinterpret_cast<float2*>(&out[(size_t)node * HID + lane * 2]) = o;
}

// ---------------- mean-pool accumulation (batch sorted: register runs) ----------------
__global__ __launch_bounds__(128)
void pool_kernel(const float* __restrict__ node_x, const int* __restrict__ batch,
                 float* __restrict__ gsum, int N) {
  const int f = threadIdx.x;
  const int i0 = blockIdx.x * 16;
  const int i1 = min(i0 + 16, N);
  float acc = 0.f; int curg = -1;
  for (int i = i0; i < i1; ++i) {
    const int g = batch[i];
    const float v = node_x[(size_t)i * HID + f];
    if (g != curg) {
      if (curg >= 0) atomicAdd(&gsum[curg * HID + f], acc);
      acc = 0.f; curg = g;
    }
    acc += v;
  }
  if (curg >= 0) atomicAdd(&gsum[curg * HID + f], acc);
}

__global__ void count_kernel(const int* __restrict__ batch, float* __restrict__ gcnt, int N) {
  int i = blockIdx.x * blockDim.x + threadIdx.x;
  if (i < N) atomicAdd(&gcnt[batch[i]], 1.f);
}

// ---------------- graph MLP ----------------
__global__ __launch_bounds__(256)
void mlp_kernel(const float* __restrict__ gsum, const float* __restrict__ gcnt,
                const float* __restrict__ w1, const float* __restrict__ b1,
                const float* __restrict__ w2, const float* __restrict__ b2,
                float* __restrict__ out) {
  const int g = blockIdx.x;
  const int t = threadIdx.x;
  __shared__ float gx[HID];
  __shared__ float red[8];
  const float cnt = fmaxf(gcnt[g], 1.f);
  if (t < HID) gx[t] = gsum[g * HID + t] / cnt;
  __syncthreads();
  float a = b1[t];
  for (int k = 0; k < HID; ++k) a = fmaf(gx[k], w1[k * 256 + t], a);
  const float h = fmaxf(a, 0.f);
  float p0 = h * w2[t * 2 + 0];
  float p1 = h * w2[t * 2 + 1];
  for (int o = 32; o > 0; o >>= 1) { p0 += __shfl_down(p0, o, 64); p1 += __shfl_down(p1, o, 64); }
  const int lane = t & 63, wv = t >> 6;
  if (lane == 0) { red[wv * 2] = p0; red[wv * 2 + 1] = p1; }
  __syncthreads();
  if (t == 0) out[g * 2 + 0] = red[0] + red[2] + red[4] + red[6] + b2[0];
  if (t == 1) out[g * 2 + 1] = red[1] + red[3] + red[5] + red[7] + b2[1];
}

extern "C" void kernel_launch(void* const* d_in, const int* in_sizes, int n_in,
                              void* d_out, int out_size, void* d_ws, size_t ws_size,
                              hipStream_t stream) {
  const float* x       = (const float*)d_in[0];
  const int*   ei      = (const int*)d_in[1];
  const float* ea      = (const float*)d_in[2];
  const int*   batch   = (const int*)d_in[3];
  const float* w_init0 = (const float*)d_in[4];
  const float* w_root0 = (const float*)d_in[5];
  const float* b0      = (const float*)d_in[6];
  const float* w_init1 = (const float*)d_in[7];
  const float* w_root1 = (const float*)d_in[8];
  const float* b1      = (const float*)d_in[9];
  const float* mw1     = (const float*)d_in[10];
  const float* mb1     = (const float*)d_in[11];
  const float* mw2     = (const float*)d_in[12];
  const float* mb2     = (const float*)d_in[13];
  float* out = (float*)d_out;

  const int E = in_sizes[2];
  const int N = in_sizes[3];
  const int* row = ei;
  const int* col = ei + E;
  const int nb = (N + 255) / 256;

  char* ws = (char*)d_ws;
  size_t off = 0;
  auto alloc = [&](size_t bytes) -> void* {
    size_t cur = off;
    off = (cur + bytes + 255) & ~(size_t)255;
    return (void*)(ws + cur);
  };
  float* deg    = (float*)alloc((size_t)N * 4);
  int*   cnt    = (int*)alloc((size_t)N * 4);
  int*   cursor = (int*)alloc((size_t)N * 4);
  int*   psum   = (int*)alloc((size_t)nb * 4);
  int*   rowptr = (int*)alloc((size_t)(N + 1) * 4);
  int*   crow   = (int*)alloc((size_t)E * 4);
  float* cnrm   = (float*)alloc((size_t)E * 4);
  float* B1     = (float*)alloc((size_t)N * HID * 4);
  float* B2     = (float*)alloc((size_t)N * HID * 4);
  float* B3     = (float*)alloc((size_t)N * HID * 4);
  unsigned short* w0h = (unsigned short*)alloc((size_t)256 * F_IN * 2);
  unsigned short* w0l = (unsigned short*)alloc((size_t)256 * F_IN * 2);
  unsigned short* w1h = (unsigned short*)alloc((size_t)256 * HID * 2);
  unsigned short* w1l = (unsigned short*)alloc((size_t)256 * HID * 2);
  float* gsum   = (float*)alloc((size_t)NGRAPH * HID * 4);
  float* gcnt   = (float*)alloc((size_t)NGRAPH * 4);
  (void)ws_size; (void)n_in; (void)out_size;

  // ---- gcn_norm + CSR build + weight prep ----
  hipMemsetAsync(deg, 0, (size_t)N * 4, stream);
  hipMemsetAsync(cnt, 0, (size_t)N * 4, stream);
  hipMemsetAsync(cursor, 0, (size_t)N * 4, stream);
  deg_kernel<<<(E + 255) / 256, 256, 0, stream>>>(col, ea, deg, E);
  dinv_kernel<<<(N + 255) / 256, 256, 0, stream>>>(deg, N);
  count_in_kernel<<<(E + 255) / 256, 256, 0, stream>>>(col, cnt, E);
  scan1_kernel<<<nb, 256, 0, stream>>>(cnt, psum, N);
  scan2_kernel<<<1, 64, 0, stream>>>(psum, nb);
  scan3_kernel<<<nb, 256, 0, stream>>>(cnt, psum, rowptr, N, E);
  fill_csr_kernel<<<(E + 255) / 256, 256, 0, stream>>>(row, col, ea, deg, rowptr, cursor,
                                                       crow, cnrm, E);
  prep_w_kernel<<<(256 * F_IN + 255) / 256, 256, 0, stream>>>(w_init0, w_root0, w0h, w0l, F_IN);
  prep_w_kernel<<<(256 * HID + 255) / 256, 256, 0, stream>>>(w_init1, w_root1, w1h, w1l, HID);

  const int gb = (N + 63) / 64;

  // ---- conv0: B1 = x@w_init0, B2 = x@w_root0; B2 <- relu(gather(B1) + B2 + b0) ----
  gemm_mfma<F_IN><<<gb, 256, 0, stream>>>(x, w0h, w0l, B1, B2, N);
  gather_kernel<<<(N + 3) / 4, 256, 0, stream>>>(rowptr, crow, cnrm, B1, B2, b0, B2, N);

  // ---- conv1: B1 = h@w_init1, B3 = h@w_root1; B3 <- relu(gather(B1) + B3 + b1) ----
  gemm_mfma<HID><<<gb, 256, 0, stream>>>(B2, w1h, w1l, B1, B3, N);
  gather_kernel<<<(N + 3) / 4, 256, 0, stream>>>(rowptr, crow, cnrm, B1, B3, b1, B3, N);

  // ---- pool + MLP ----
  hipMemsetAsync(gsum, 0, (size_t)NGRAPH * HID * 4, stream);
  hipMemsetAsync(gcnt, 0, (size_t)NGRAPH * 4, stream);
  pool_kernel<<<(N + 15) / 16, 128, 0, stream>>>(B3, batch, gsum, N);
  count_kernel<<<(N + 255) / 256, 256, 0, stream>>>(batch, gcnt, N);
  mlp_kernel<<<NGRAPH, 256, 0, stream>>>(gsum, gcnt, mw1, mb1, mw2, mb2, out);
}